// Round 6
// baseline (982.185 us; speedup 1.0000x reference)
//
#include <hip/hip_runtime.h>

// LittleBitITQSpecLinear: y = sum_b ((x*v2_b) @ sign(V_b)^T * (v1_b*u2_b)) @ sign(U_b)^T * u1_b + bias
// Folded: W1_b[s,k] = sign(V_b[s,k])*v2_b[k];  W2_b[o,s] = sign(U_b[o,s])*v1_b[s]*u2_b[s]*u1_b[o]
// => H = Xbf16 @ W1cat^T  (8192x2048, K=4096);  Y = H @ W2cat^T + bias (8192x4096, K=2048)
//
// R8: one-phase-ahead fragment reads with COUNTED lgkm. R7 measured exactly
// the serial model (reads 2300cy + MFMA 2048cy per K-tile = 2.03us observed):
// its [reads; BAR; LGKM(0); MFMA] skeleton drains reads before every MFMA.
// New skeleton: [stage; (VMW); BAR_a; reads(p+1); LGKM(N=|reads(p+1)|) ->
// drains only reads(p); MFMA(p); BAR_b] -- phase p's MFMA covers p+1's reads.
// Balanced read slots {4,8,4,8,...}: ph1 b1(e), ph2 a1(e), ph3 b0B(o),
// ph4 a0(o), ph5 b1(o), ph6 a1(o), ph7 b0A(f), ph8 a0(f). Publish moved to
// VMW(4) at ph3/ph7 (queue=12 -> retires exactly the 8 loads of the tile
// consumed next; youngest retired has 2 phases ~1300cy cover). b0 double-
// registered (b0A even / b0B odd tiles; lifetimes overlap at ph4/ph8).
// WAR: reads of X issued ph r are drained by the counted LGKM at r+1 (before
// BAR_b(r+1)); X staged at r+3 in all 8 regions -> every LDS overwrite is
// >=1 full barrier after the last read COMPLETION (same class R5/R7 proved).
// LGKM ledger: out = {12->4, 4+8->8, 8+4->4, 4+8(skip), 12->4, ...} audited.

typedef __bf16 bf16x8 __attribute__((ext_vector_type(8)));
typedef float floatx4 __attribute__((ext_vector_type(4)));

__device__ __forceinline__ unsigned short f2bf_rne(float f) {
    union { float f; unsigned u; } v; v.f = f;
    unsigned r = v.u + 0x7FFFu + ((v.u >> 16) & 1u);
    return (unsigned short)(r >> 16);
}

__device__ __forceinline__ float sgnf(float w) {
    return (float)((w > 0.f) - (w < 0.f));
}

__device__ __forceinline__ void async_copy16(const void* g, void* l) {
    __builtin_amdgcn_global_load_lds(
        (const __attribute__((address_space(1))) void*)g,
        (__attribute__((address_space(3))) void*)l, 16, 0, 0);
}

#define FENCE() asm volatile("" ::: "memory")
#define BAR() do { FENCE(); __builtin_amdgcn_s_barrier(); FENCE(); } while (0)
#define VMW(N) asm volatile("s_waitcnt vmcnt(" #N ")" ::: "memory")
#define LGKM(N) asm volatile("s_waitcnt lgkmcnt(" #N ")" ::: "memory")

// ---------------- fused prep kernel (unchanged, proven) ----------------
// Blocks [0,32768): cast x -> bf16. [32768,40960): W1cat. [40960,49152): W2cat.

__global__ void prep_all_kernel(const float* __restrict__ x,
                                unsigned short* __restrict__ xb,
                                const float* __restrict__ V, const float* __restrict__ V_R,
                                const float* __restrict__ v2, const float* __restrict__ v2_R,
                                const float* __restrict__ U, const float* __restrict__ U_R,
                                const float* __restrict__ v1, const float* __restrict__ v1_R,
                                const float* __restrict__ u2, const float* __restrict__ u2_R,
                                const float* __restrict__ u1, const float* __restrict__ u1_R,
                                unsigned short* __restrict__ W1,
                                unsigned short* __restrict__ W2) {
    int bid = blockIdx.x;
    if (bid < 32768) {
        int i = bid * blockDim.x + threadIdx.x;
        float4 v = ((const float4*)x)[i];
        ushort4 o;
        o.x = f2bf_rne(v.x); o.y = f2bf_rne(v.y);
        o.z = f2bf_rne(v.z); o.w = f2bf_rne(v.w);
        ((ushort4*)xb)[i] = o;
    } else if (bid < 40960) {
        int i = (bid - 32768) * blockDim.x + threadIdx.x;
        int idx = i << 2;
        int scat = idx >> 12;
        int k = idx & 4095;
        const float* Vp; const float* sp;
        if (scat < 1024) { Vp = V + ((size_t)scat << 12); sp = v2; }
        else             { Vp = V_R + ((size_t)(scat - 1024) << 12); sp = v2_R; }
        float4 w = *(const float4*)(Vp + k);
        float4 s = *(const float4*)(sp + k);
        ushort4 o;
        o.x = f2bf_rne(sgnf(w.x) * s.x);
        o.y = f2bf_rne(sgnf(w.y) * s.y);
        o.z = f2bf_rne(sgnf(w.z) * s.z);
        o.w = f2bf_rne(sgnf(w.w) * s.w);
        ((ushort4*)W1)[i] = o;
    } else {
        int i = (bid - 40960) * blockDim.x + threadIdx.x;
        int idx = i << 2;
        int o = idx >> 11;
        int scat = idx & 2047;
        int branch = scat >> 10;
        int s = scat & 1023;
        const float* Up  = branch ? U_R  : U;
        const float* v1p = branch ? v1_R : v1;
        const float* u2p = branch ? u2_R : u2;
        float u1v = (branch ? u1_R : u1)[o];
        float4 w = *(const float4*)(Up + ((size_t)o << 10) + s);
        float4 a = *(const float4*)(v1p + s);
        float4 b = *(const float4*)(u2p + s);
        ushort4 out;
        out.x = f2bf_rne(sgnf(w.x) * a.x * b.x * u1v);
        out.y = f2bf_rne(sgnf(w.y) * a.y * b.y * u1v);
        out.z = f2bf_rne(sgnf(w.z) * a.z * b.z * u1v);
        out.w = f2bf_rne(sgnf(w.w) * a.w * b.w * u1v);
        ((ushort4*)W2)[i] = out;
    }
}

// ---------------- GEMM: C[M,N] = A[M,K] @ B[N,K]^T ----------------
// 256x256 tile, BK=64, 512 threads = 8 waves (2M x 4N), per-wave 128x64 out.
// LDS slice regions (8 KiB each): As[buf][mh] (A rows mh*64..), Bs[buf][nh].
// Stage slot map (iter i: e=2i buf0, o=2i+1 buf1 consumed; f=2i+2, g=2i+3):
//   ph1 o.A1, ph2 f.B0, ph3 f.A0, ph4 f.B1, ph5 f.A1, ph6 g.B0, ph7 g.A0,
//   ph8 g.B1 (g.A1 staged next iter ph1).

template <bool OUT_BF16, bool ADD_BIAS>
__global__ __launch_bounds__(512, 2)
void gemm256(const unsigned short* __restrict__ A,
             const unsigned short* __restrict__ B,
             void* __restrict__ Cv,
             const float* __restrict__ bias,
             int M, int N, int K, int ntn) {
    (void)M;
    __shared__ __align__(16) unsigned short As[2][2][128 * 64];
    __shared__ __align__(16) unsigned short Bs[2][2][128 * 64];

    const int tid = threadIdx.x;
    const int lane = tid & 63;
    const int wave = tid >> 6;
    const int warp_m = wave >> 2;   // 0..1
    const int warp_n = wave & 3;    // 0..3

    // XCD-aware swizzle (nwg % 8 == 0 for both GEMMs -> bijective)
    const int nwg = gridDim.x;
    const int hw = blockIdx.x;
    const int swz = (hw & 7) * (nwg >> 3) + (hw >> 3);
    const int tm = swz / ntn;
    const int tn = swz - tm * ntn;
    const int m0 = tm << 8;
    const int n0 = tn << 8;

    const int srow = tid >> 3;                          // 0..63
    const int scg8 = (((tid & 7) ^ (srow & 7)) << 3);   // swizzled chunk * 8
    const int ldst = tid << 3;                          // 0..4095 elems
    const size_t Ks = (size_t)K;

    auto stA = [&](int buf, int mh, int kt) {
        const unsigned short* g = A + (size_t)(m0 + (mh << 6) + srow) * Ks + (kt << 6) + scg8;
        async_copy16(g,             &As[buf][mh][ldst]);
        async_copy16(g + (Ks << 7), &As[buf][mh][4096 + ldst]);
    };
    auto stB = [&](int buf, int nh, int kt) {
        const unsigned short* g = B + (size_t)(n0 + ((srow >> 5) << 6) + (nh << 5) + (srow & 31)) * Ks
                                    + (kt << 6) + scg8;
        async_copy16(g,             &Bs[buf][nh][ldst]);
        async_copy16(g + (Ks << 7), &Bs[buf][nh][4096 + ldst]);
    };

    // fragment reads (read-side swizzle matches fetch-side; proven R0/R5/R7)
    const int fm = lane & 15;
    const int cgl = lane >> 4;                // 0..3
    const int key = fm & 7;
    const int ok0 = ((cgl ^ key) << 3);       // elem offset, k-slice 0
    const int ok1 = (((4 | cgl) ^ key) << 3); // elem offset, k-slice 1

    auto lda = [&](bf16x8 (&dst)[4][2], int buf, int mh) {
        const unsigned short* base = &As[buf][mh][0];
#pragma unroll
        for (int mi = 0; mi < 4; ++mi) {
            const unsigned short* p = base + (((warp_m << 6) + (mi << 4) + fm) << 6);
            dst[mi][0] = *(const bf16x8*)(p + ok0);
            dst[mi][1] = *(const bf16x8*)(p + ok1);
        }
    };
    auto ldb = [&](bf16x8 (&dst)[2][2], int buf, int nh) {
        const unsigned short* base = &Bs[buf][nh][0];
#pragma unroll
        for (int ni = 0; ni < 2; ++ni) {
            const unsigned short* p = base + (((warp_n << 5) + (ni << 4) + fm) << 6);
            dst[ni][0] = *(const bf16x8*)(p + ok0);
            dst[ni][1] = *(const bf16x8*)(p + ok1);
        }
    };

    floatx4 acc[8][4];
#pragma unroll
    for (int i = 0; i < 8; ++i)
#pragma unroll
        for (int j = 0; j < 4; ++j)
#pragma unroll
            for (int r = 0; r < 4; ++r) acc[i][j][r] = 0.f;

    // a0/a1/b1 single sets (lifetimes disjoint across tiles);
    // b0 double-registered: b0A = even-tile B0 slice, b0B = odd-tile.
    bf16x8 a0[4][2], a1[4][2], b0A[2][2], b0B[2][2], b1[2][2];

#define MMAQ(aS, bS, MH, NH) do { \
    __builtin_amdgcn_s_setprio(1); \
    _Pragma("unroll") \
    for (int mi_ = 0; mi_ < 4; ++mi_) { \
      _Pragma("unroll") \
      for (int ni_ = 0; ni_ < 2; ++ni_) { \
        acc[(MH)*4 + mi_][(NH)*2 + ni_] = __builtin_amdgcn_mfma_f32_16x16x32_bf16( \
            aS[mi_][0], bS[ni_][0], acc[(MH)*4 + mi_][(NH)*2 + ni_], 0, 0, 0); \
        acc[(MH)*4 + mi_][(NH)*2 + ni_] = __builtin_amdgcn_mfma_f32_16x16x32_bf16( \
            aS[mi_][1], bS[ni_][1], acc[(MH)*4 + mi_][(NH)*2 + ni_], 0, 0, 0); \
      } } \
    __builtin_amdgcn_s_setprio(0); \
  } while (0)

    // ---- prologue: t0 all 4 slices + t1.{B0,A0,B1} = 14 loads;
    // VMW(6) retires t0's 8 -> resident; queue = t1.{B0,A0,B1} (invariant).
    stB(0, 0, 0); stA(0, 0, 0); stB(0, 1, 0); stA(0, 1, 0);
    stB(1, 0, 1); stA(1, 0, 1); stB(1, 1, 1);
    VMW(6);
    BAR();
    // pre-issue reads for ph1's MFMA (tile t0 Q00): a0 + b0A. Out lgkm = 12.
    lda(a0, 0, 0); ldb(b0A, 0, 0);

    const int NT = K >> 6;
    for (int i = 0; i < (NT >> 1) - 1; ++i) {
        const int okt = 2 * i + 1, fk = 2 * i + 2, gk = 2 * i + 3;
        // ph1: Q00(e). reads b1(e); LGKM(4) drains a0,b0A (12).
        stA(1, 1, okt);
        BAR();
        ldb(b1, 0, 1);
        LGKM(4);
        MMAQ(a0, b0A, 0, 0);
        BAR();
        // ph2: Q01(e). reads a1(e); LGKM(8) drains b1 (4).
        stB(0, 0, fk);
        BAR();
        lda(a1, 0, 1);
        LGKM(8);
        MMAQ(a0, b1, 0, 1);
        BAR();
        // ph3: Q11(e). VMW(4): queue [o.B0,A0,B1,A1,f.B0,f.A0]=12 -> retires
        // tile o (youngest o.A1 staged ph1, 2 phases cover). Publish BAR.
        // reads b0B(o); LGKM(4) drains a1 (8).
        stA(0, 0, fk);
        VMW(4);
        BAR();
        ldb(b0B, 1, 0);
        LGKM(4);
        MMAQ(a1, b1, 1, 1);
        BAR();
        // ph4: Q10(e) on a1,b0A (both drained). reads a0(o); no LGKM ->
        // MFMA covers the 8-read burst + b0B still in flight.
        stB(0, 1, fk);
        BAR();
        lda(a0, 1, 0);
        MMAQ(a1, b0A, 1, 0);
        BAR();
        // ph5: Q00(o). reads b1(o); LGKM(4) drains b0B+a0 (12).
        stA(0, 1, fk);
        BAR();
        ldb(b1, 1, 1);
        LGKM(4);
        MMAQ(a0, b0B, 0, 0);
        BAR();
        // ph6: Q01(o). reads a1(o); LGKM(8) drains b1 (4).
        stB(1, 0, gk);
        BAR();
        lda(a1, 1, 1);
        LGKM(8);
        MMAQ(a0, b1, 0, 1);
        BAR();
        // ph7: Q11(o). VMW(4): queue [f.B0,A0,B1,A1,g.B0,g.A0]=12 -> retires
        // tile f. Publish BAR. reads b0A(f); LGKM(4) drains a1 (8).
        stA(1, 0, gk);
        VMW(4);
        BAR();
        ldb(b0A, 0, 0);
        LGKM(4);
        MMAQ(a1, b1, 1, 1);
        BAR();
        // ph8: Q10(o) on a1,b0B (drained). reads a0(f); no LGKM.
        stB(1, 1, gk);
        BAR();
        lda(a0, 0, 0);
        MMAQ(a1, b0B, 1, 0);
        BAR();
    }
    // ---- epilogue: tiles E=NT-2 (buf0), O=NT-1 (buf1).
    // Entering: vm queue = O.{B0,A0,B1} (6); lgkm out = a0,b0A of E (12).
    {
        // E1
        stA(1, 1, NT - 1);
        BAR();
        ldb(b1, 0, 1);
        LGKM(4);
        MMAQ(a0, b0A, 0, 0);
        BAR();
        // E2
        lda(a1, 0, 1);
        LGKM(8);
        MMAQ(a0, b1, 0, 1);
        BAR();
        // E3: publish O entirely (VMW(0): oldest 5+ phases, O.A1 2 phases).
        VMW(0);
        BAR();
        ldb(b0B, 1, 0);
        LGKM(4);
        MMAQ(a1, b1, 1, 1);
        BAR();
        // E4..E8: no LDS writes remain -> barrier-free pipelined tail.
        lda(a0, 1, 0);
        MMAQ(a1, b0A, 1, 0);
        ldb(b1, 1, 1);
        LGKM(4);
        MMAQ(a0, b0B, 0, 0);
        lda(a1, 1, 1);
        LGKM(8);
        MMAQ(a0, b1, 0, 1);
        LGKM(0);
        MMAQ(a1, b1, 1, 1);
        MMAQ(a1, b0B, 1, 0);
    }
#undef MMAQ

    // epilogue C-write: C/D layout col=lane&15, row=(lane>>4)*4+reg [m89]
    const int rq = (lane >> 4) << 2;
    const int col = lane & 15;
#pragma unroll
    for (int mi = 0; mi < 8; ++mi) {
#pragma unroll
        for (int r = 0; r < 4; ++r) {
            const int gm = m0 + (warp_m << 7) + (mi << 4) + rq + r;
            const size_t base = (size_t)gm * (size_t)N;
#pragma unroll
            for (int ni = 0; ni < 4; ++ni) {
                const int gn = n0 + (warp_n << 6) + (ni << 4) + col;
                float v = acc[mi][ni][r];
                if (ADD_BIAS) v += bias[gn];
                if (OUT_BF16)
                    ((unsigned short*)Cv)[base + gn] = f2bf_rne(v);
                else
                    ((float*)Cv)[base + gn] = v;
            }
        }
    }
}

// ---------------- launch ----------------

extern "C" void kernel_launch(void* const* d_in, const int* in_sizes, int n_in,
                              void* d_out, int out_size, void* d_ws, size_t ws_size,
                              hipStream_t stream) {
    const float* x    = (const float*)d_in[0];
    const float* V    = (const float*)d_in[1];
    const float* U    = (const float*)d_in[2];
    const float* v2   = (const float*)d_in[3];
    const float* v1   = (const float*)d_in[4];
    const float* u2   = (const float*)d_in[5];
    const float* u1   = (const float*)d_in[6];
    const float* V_R  = (const float*)d_in[7];
    const float* U_R  = (const float*)d_in[8];
    const float* v2_R = (const float*)d_in[9];
    const float* v1_R = (const float*)d_in[10];
    const float* u2_R = (const float*)d_in[11];
    const float* u1_R = (const float*)d_in[12];
    const float* bias = (const float*)d_in[13];
    float* out = (float*)d_out;

    char* ws = (char*)d_ws;
    unsigned short* Xb = (unsigned short*)ws;                                   // 64 MiB
    unsigned short* W1 = (unsigned short*)(ws + (size_t)67108864);              // 16 MiB
    unsigned short* W2 = (unsigned short*)(ws + (size_t)67108864 + 16777216);   // 16 MiB
    unsigned short* H  = (unsigned short*)(ws + (size_t)67108864 + 33554432);   // 32 MiB

    // fused prep: 32768 cast blocks + 8192 W1 blocks + 8192 W2 blocks
    prep_all_kernel<<<49152, 256, 0, stream>>>(x, Xb, V, V_R, v2, v2_R,
                                               U, U_R, v1, v1_R, u2, u2_R, u1, u1_R,
                                               W1, W2);

    // GEMM1: H[8192,2048] = Xb @ W1^T, K=4096  -> 32x8 = 256 tiles (1/CU)
    gemm256<true, false><<<dim3(256), 512, 0, stream>>>(Xb, W1, (void*)H, nullptr,
                                                        8192, 2048, 4096, 8);
    // GEMM2: Y[8192,4096] = H @ W2^T + bias, K=2048 -> 32x16 = 512 tiles (2/CU)
    gemm256<false, true><<<dim3(512), 512, 0, stream>>>(H, W2, (void*)out, bias,
                                                        8192, 4096, 2048, 16);
}